// Round 7
// baseline (54.586 us; speedup 1.0000x reference)
//
#include <hip/hip_runtime.h>
#include <hip/hip_bf16.h>

#define NB   16
#define CINC 64
#define COUTC 64
#define NV   25
#define TLEN 512
#define KK   3
#define TKK  3

typedef short short8 __attribute__((ext_vector_type(8)));
typedef float f32x4  __attribute__((ext_vector_type(4)));
typedef float f32x16 __attribute__((ext_vector_type(16)));

#define XT_ROWS 514        // padded: row 0 = t=-1 (zero), rows 1..512 = t, row 513 = t=512 (zero)
#define XS_BYTES 16640     // 130 rows * 128 B per slab buffer
#define NWT3BLK (NV * 9)   // 225 weight-prep blocks

__device__ __forceinline__ unsigned pack_bf16(float lo, float hi) {
  __hip_bfloat16 l = __float2bfloat16(lo);
  __hip_bfloat16 h = __float2bfloat16(hi);
  unsigned short ul = *reinterpret_cast<unsigned short*>(&l);
  unsigned short uh = *reinterpret_cast<unsigned short*>(&h);
  return (unsigned)ul | ((unsigned)uh << 16);
}

// ================= fused prep: Wt3 (blocks 0..224) + padded xT (rest) ========
// Wt3[blk=(v*3+k)*3+kt][oslab][ks][lane][e] bf16, mask folded in.
//   o = oslab*32 + (lane&31);  c = ks*16 + 8*(lane>>5) + e
// xT[n][v][rp][c] bf16, rp = t+1, rows 0 and 513 zeroed.
__global__ __launch_bounds__(256) void prep_all(
    const float* __restrict__ x, const float* __restrict__ W,
    const unsigned char* __restrict__ mask_raw,
    __hip_bfloat16* __restrict__ Wt3, __hip_bfloat16* __restrict__ xT) {
  __shared__ float ts[64][65];
  int bid = blockIdx.x;
  if (bid < NWT3BLK) {
    int blk = bid;                 // v*9 + k*3 + kt
    int v = blk / 9, kkt = blk % 9, k = kkt / 3, kt = kkt % 3;
    const int* mi = (const int*)mask_raw;
    int ok = 1;
    for (int i = 0; i < 18; ++i) {
      int m = mi[i];
      if (m != 0 && m != 1) ok = 0;
    }
    int m = ok ? mi[v * KK + k] : (int)(mask_raw[v * KK + k] != 0);
    const float* Wv = W + (size_t)v * COUTC * CINC * 9;
    __hip_bfloat16* dst = Wt3 + (size_t)blk * 4096;
    for (int i = threadIdx.x; i < 4096; i += 256) {
      int e     = i & 7;
      int lane  = (i >> 3) & 63;
      int ks    = (i >> 9) & 3;
      int oslab = i >> 11;
      int o = oslab * 32 + (lane & 31);
      int c = ks * 16 + 8 * (lane >> 5) + e;
      float val = m ? Wv[(o * CINC + c) * 9 + k * 3 + kt] : 0.f;
      dst[i] = __float2bfloat16(val);
    }
    return;
  }
  bid -= NWT3BLK;
  const int tb = (bid & 7) * 64;
  const int vn = bid >> 3;
  const int v  = vn % NV;
  const int n  = vn / NV;
  const int tid = threadIdx.x;
  // load: float4 over t (coalesced), transpose via LDS (stride 65: <=2-way)
  for (int i = tid; i < 1024; i += 256) {
    int c = i >> 4, tq = (i & 15) * 4;
    float4 val = *(const float4*)(x + (((size_t)n * CINC + c) * NV + v) * TLEN + tb + tq);
    ts[c][tq + 0] = val.x;
    ts[c][tq + 1] = val.y;
    ts[c][tq + 2] = val.z;
    ts[c][tq + 3] = val.w;
  }
  __syncthreads();
  // emit packed bf16 pairs; 256 B contiguous per wave-instr
  unsigned* base = (unsigned*)(xT + ((size_t)(n * NV + v) * XT_ROWS) * CINC);
  for (int i = tid; i < 2048; i += 256) {
    int c2 = i & 31, t = i >> 5;
    base[(tb + 1 + t) * 32 + c2] = pack_bf16(ts[2 * c2][t], ts[2 * c2 + 1][t]);
  }
  // zero halo rows
  if (tb == 0 && tid < 32) base[tid] = 0u;
  if (tb == TLEN - 64 && tid < 32) base[513 * 32 + tid] = 0u;
}

__device__ __forceinline__ const char* slab_base(const __hip_bfloat16* xT,
                                                 int n, int vk, int tb) {
  return (const char*)xT + ((size_t)(n * NV + vk) * XT_ROWS + tb) * 128;
}

// Main: block = 64 o x 128 t x 1 n for (tchunk, n, v). 4 waves; wave owns a
// 32-t quarter, computes both o-slabs. R6 lesson: per-block latency (not any
// pipe) dominated -- so stage ALL 3 neighbor slabs up-front (49.9 KB LDS, 3
// blocks/CU) behind ONE barrier, then run the whole 144-MFMA chain straight-
// line with zero further sync. 12 waves/CU drift freely and hide each other.
__global__ __launch_bounds__(256) void lcn_mfma32(
    const __hip_bfloat16* __restrict__ xT,
    const __hip_bfloat16* __restrict__ Wt3,
    const float* __restrict__ bias,
    const int* __restrict__ idx,
    float* __restrict__ out) {
  __shared__ char xs[KK][XS_BYTES];   // 3 slabs, 49,920 B

  const int tb   = blockIdx.x * 128;
  const int n    = blockIdx.y;
  const int v    = blockIdx.z;
  const int tid  = threadIdx.x;
  const int lane = tid & 63;
  const int wave = tid >> 6;
  const int wt   = wave * 32;
  const int hi   = lane >> 5;
  const int l31  = lane & 31;

  // single-shot stage of all 3 neighbor slabs (linear LDS dest,
  // involution-swizzled global source; zero-padded xT rows cover the halo)
  {
    const char* g0 = slab_base(xT, n, idx[v * KK + 0], tb);
    const char* g1 = slab_base(xT, n, idx[v * KK + 1], tb);
    const char* g2 = slab_base(xT, n, idx[v * KK + 2], tb);
    for (int j = wave; j < 3 * 17; j += 4) {
      int slab = j / 17, c = j % 17;
      const char* gb = slab == 0 ? g0 : (slab == 1 ? g1 : g2);
      int L = c * 1024 + lane * 16;
      if (L < XS_BYTES) {
        int g = L ^ (((L >> 7) & 7) << 4);   // XOR bits 4-6 by row bits 7-9
        __builtin_amdgcn_global_load_lds(
            (const __attribute__((address_space(1))) void*)(gb + g),
            (__attribute__((address_space(3))) void*)(&xs[slab][c * 1024]),
            16, 0, 0);
      }
    }
  }
  __syncthreads();   // the only barrier in the kernel

  f32x16 acc0 = {}, acc1 = {};   // o-slab 0 / 1
  const short8* wbase = (const short8*)Wt3;

#pragma unroll
  for (int k = 0; k < KK; ++k) {
    const char* cb = xs[k];
    const int blk0 = (v * KK + k) * TKK;
#pragma unroll
    for (int kt = 0; kt < TKK; ++kt) {
      short8 a0[4], a1[4];
      {
        const short8* p0 = wbase + (((blk0 + kt) * 2 + 0) << 8) + lane;
        const short8* p1 = wbase + (((blk0 + kt) * 2 + 1) << 8) + lane;
#pragma unroll
        for (int ks = 0; ks < 4; ++ks) {
          a0[ks] = p0[ks << 6];
          a1[ks] = p1[ks << 6];
        }
      }
      const int r  = wt + l31 + kt;
      const int sw = (r & 7) << 4;
      const int co = hi * 16;
      const char* bp = cb + r * 128;
#pragma unroll
      for (int ks = 0; ks < 4; ++ks) {
        short8 bfr = *(const short8*)(bp + ((co + 32 * ks) ^ sw));
        acc0 = __builtin_amdgcn_mfma_f32_32x32x16_bf16(a0[ks], bfr, acc0, 0, 0, 0);
        acc1 = __builtin_amdgcn_mfma_f32_32x32x16_bf16(a1[ks], bfr, acc1, 0, 0, 0);
      }
    }
  }

  // epilogue: D col(t)=lane&31, row(o)=(reg&3)+8*(reg>>2)+4*(lane>>5)
  const float* bv = bias + v * COUTC;
  const int t = tb + wt + l31;
#pragma unroll
  for (int os = 0; os < 2; ++os) {
    const f32x16& acc = os ? acc1 : acc0;
#pragma unroll
    for (int reg = 0; reg < 16; ++reg) {
      int o = os * 32 + 4 * hi + (reg & 3) + 8 * (reg >> 2);
      out[(((size_t)n * COUTC + o) * NV + v) * TLEN + t] = acc[reg] + bv[o];
    }
  }
}

// ================= FALLBACK PATH (round-1 fp32, known-good) =================
__global__ void prep_mask_kernel(const int* __restrict__ mask_raw,
                                 int* __restrict__ mask_out) {
  __shared__ int fmt;
  if (threadIdx.x == 0) {
    int ok = 1;
    for (int i = 0; i < 18; ++i) {
      int m = mask_raw[i];
      if (m != 0 && m != 1) ok = 0;
    }
    fmt = ok;
  }
  __syncthreads();
  int i = threadIdx.x;
  if (i < NV * KK) {
    int m;
    if (fmt) m = mask_raw[i];
    else     m = (((const unsigned char*)mask_raw)[i] != 0) ? 1 : 0;
    mask_out[i] = m;
  }
}

__global__ void prep_wt_kernel(const float* __restrict__ W,
                               float* __restrict__ Wt) {
  int v   = blockIdx.x / 9;
  int kkt = blockIdx.x % 9;
  const float* Wv = W + (size_t)v * COUTC * CINC * 9;
  float* dst = Wt + (size_t)blockIdx.x * (CINC * COUTC);
  for (int i = threadIdx.x; i < CINC * COUTC; i += 256) {
    int c = i >> 6;
    int o = i & 63;
    dst[i] = Wv[(o * CINC + c) * 9 + kkt];
  }
}

__global__ __launch_bounds__(256, 4) void lcn_main(
    const float* __restrict__ x, const float* __restrict__ Wt,
    const float* __restrict__ b, const int* __restrict__ idx,
    const int* __restrict__ maskn, float* __restrict__ out) {
  __shared__ float xsf[CINC][66];
  __shared__ float wsh[CINC][COUTC];
  const int tb  = blockIdx.x * 64;
  const int v   = blockIdx.y;
  const int n   = blockIdx.z;
  const int tid = threadIdx.x;
  const int t0  = tid & 63;
  const int og  = tid >> 6;
  float acc[16];
#pragma unroll
  for (int j = 0; j < 16; ++j) acc[j] = 0.f;
  for (int k = 0; k < KK; ++k) {
    const int vk = idx[v * KK + k];
    const int mk = maskn[v * KK + k];
    __syncthreads();
    for (int i = tid; i < CINC * 66; i += 256) {
      int c  = i / 66;
      int tt = i - c * 66;
      int gt = tb - 1 + tt;
      float val = 0.f;
      if (mk && gt >= 0 && gt < TLEN)
        val = x[(((size_t)n * CINC + c) * NV + vk) * TLEN + gt];
      xsf[c][tt] = val;
    }
    for (int kt = 0; kt < TKK; ++kt) {
      __syncthreads();
      const float4* src =
          (const float4*)(Wt + ((size_t)(v * KK + k) * TKK + kt) * (CINC * COUTC));
      for (int i = tid; i < CINC * COUTC / 4; i += 256)
        ((float4*)wsh)[i] = src[i];
      __syncthreads();
#pragma unroll 4
      for (int c = 0; c < CINC; ++c) {
        float xv = xsf[c][t0 + kt];
        const float4* wrow = (const float4*)&wsh[c][og * 16];
#pragma unroll
        for (int j4 = 0; j4 < 4; ++j4) {
          float4 wv = wrow[j4];
          acc[j4 * 4 + 0] = fmaf(wv.x, xv, acc[j4 * 4 + 0]);
          acc[j4 * 4 + 1] = fmaf(wv.y, xv, acc[j4 * 4 + 1]);
          acc[j4 * 4 + 2] = fmaf(wv.z, xv, acc[j4 * 4 + 2]);
          acc[j4 * 4 + 3] = fmaf(wv.w, xv, acc[j4 * 4 + 3]);
        }
      }
    }
  }
#pragma unroll
  for (int j = 0; j < 16; ++j) {
    int o = og * 16 + j;
    out[(((size_t)n * COUTC + o) * NV + v) * TLEN + tb + t0] =
        acc[j] + b[v * COUTC + o];
  }
}

extern "C" void kernel_launch(void* const* d_in, const int* in_sizes, int n_in,
                              void* d_out, int out_size, void* d_ws, size_t ws_size,
                              hipStream_t stream) {
  const float* x    = (const float*)d_in[0];
  const float* W    = (const float*)d_in[1];
  const float* b    = (const float*)d_in[2];
  const int*   idx  = (const int*)d_in[3];
  const void*  mask = (const void*)d_in[4];
  float* out = (float*)d_out;

  // ws: [0,512) maskn (fallback) | Wt3 1.84MB | xT padded 26.3MB | guard
  const size_t WT3_BYTES = (size_t)NV * 9 * 4096 * sizeof(__hip_bfloat16);
  const size_t XT_BYTES  = (size_t)NB * NV * XT_ROWS * CINC * sizeof(__hip_bfloat16);
  const size_t NEED      = 512 + WT3_BYTES + XT_BYTES + 2048;

  if (ws_size >= NEED) {
    __hip_bfloat16* Wt3 = (__hip_bfloat16*)((char*)d_ws + 512);
    __hip_bfloat16* xT  = (__hip_bfloat16*)((char*)d_ws + 512 + WT3_BYTES);
    hipLaunchKernelGGL(prep_all, dim3(NWT3BLK + 8 * NV * NB), dim3(256), 0,
                       stream, x, W, (const unsigned char*)mask, Wt3, xT);
    hipLaunchKernelGGL(lcn_mfma32, dim3(TLEN / 128, NB, NV), dim3(256), 0,
                       stream, xT, Wt3, b, idx, out);
  } else {
    int*   maskn = (int*)d_ws;
    float* Wt    = (float*)((char*)d_ws + 512);
    hipLaunchKernelGGL(prep_mask_kernel, dim3(1), dim3(128), 0, stream,
                       (const int*)mask, maskn);
    hipLaunchKernelGGL(prep_wt_kernel, dim3(NV * KK * TKK), dim3(256), 0, stream,
                       W, Wt);
    hipLaunchKernelGGL(lcn_main, dim3(TLEN / 64, NV, NB), dim3(256), 0, stream,
                       x, Wt, b, idx, maskn, out);
  }
}

// Round 8
// 50.628 us; speedup vs baseline: 1.0782x; 1.0782x over previous
//
#include <hip/hip_runtime.h>
#include <hip/hip_bf16.h>

#define NB   16
#define CINC 64
#define COUTC 64
#define NV   25
#define TLEN 512
#define KK   3
#define TKK  3

typedef short short8 __attribute__((ext_vector_type(8)));
typedef float f32x4  __attribute__((ext_vector_type(4)));
typedef float f32x16 __attribute__((ext_vector_type(16)));

#define XT_ROWS 514        // padded: row 0 = t=-1 (zero), rows 1..512 = t, row 513 = t=512 (zero)
#define XS_BYTES 16640     // 130 rows * 128 B per slab buffer
#define NWT3BLK (NV * 9)   // 225 weight-prep blocks

__device__ __forceinline__ unsigned pack_bf16(float lo, float hi) {
  __hip_bfloat16 l = __float2bfloat16(lo);
  __hip_bfloat16 h = __float2bfloat16(hi);
  unsigned short ul = *reinterpret_cast<unsigned short*>(&l);
  unsigned short uh = *reinterpret_cast<unsigned short*>(&h);
  return (unsigned)ul | ((unsigned)uh << 16);
}

// ================= fused prep: Wt3 (blocks 0..224) + padded xT (rest) ========
// Wt3[blk=(v*3+k)*3+kt][oslab][ks][lane][e] bf16, mask folded in.
//   o = oslab*32 + (lane&31);  c = ks*16 + 8*(lane>>5) + e
// xT[n][v][rp][c] bf16, rp = t+1, rows 0 and 513 zeroed.
__global__ __launch_bounds__(256) void prep_all(
    const float* __restrict__ x, const float* __restrict__ W,
    const unsigned char* __restrict__ mask_raw,
    __hip_bfloat16* __restrict__ Wt3, __hip_bfloat16* __restrict__ xT) {
  __shared__ float ts[64][65];
  int bid = blockIdx.x;
  if (bid < NWT3BLK) {
    int blk = bid;                 // v*9 + k*3 + kt
    int v = blk / 9, kkt = blk % 9, k = kkt / 3, kt = kkt % 3;
    const int* mi = (const int*)mask_raw;
    int ok = 1;
    for (int i = 0; i < 18; ++i) {
      int m = mi[i];
      if (m != 0 && m != 1) ok = 0;
    }
    int m = ok ? mi[v * KK + k] : (int)(mask_raw[v * KK + k] != 0);
    const float* Wv = W + (size_t)v * COUTC * CINC * 9;
    __hip_bfloat16* dst = Wt3 + (size_t)blk * 4096;
    for (int i = threadIdx.x; i < 4096; i += 256) {
      int e     = i & 7;
      int lane  = (i >> 3) & 63;
      int ks    = (i >> 9) & 3;
      int oslab = i >> 11;
      int o = oslab * 32 + (lane & 31);
      int c = ks * 16 + 8 * (lane >> 5) + e;
      float val = m ? Wv[(o * CINC + c) * 9 + k * 3 + kt] : 0.f;
      dst[i] = __float2bfloat16(val);
    }
    return;
  }
  bid -= NWT3BLK;
  const int tb = (bid & 7) * 64;
  const int vn = bid >> 3;
  const int v  = vn % NV;
  const int n  = vn / NV;
  const int tid = threadIdx.x;
  // load: float4 over t (coalesced), transpose via LDS (stride 65: <=2-way)
  for (int i = tid; i < 1024; i += 256) {
    int c = i >> 4, tq = (i & 15) * 4;
    float4 val = *(const float4*)(x + (((size_t)n * CINC + c) * NV + v) * TLEN + tb + tq);
    ts[c][tq + 0] = val.x;
    ts[c][tq + 1] = val.y;
    ts[c][tq + 2] = val.z;
    ts[c][tq + 3] = val.w;
  }
  __syncthreads();
  // emit packed bf16 pairs; 256 B contiguous per wave-instr
  unsigned* base = (unsigned*)(xT + ((size_t)(n * NV + v) * XT_ROWS) * CINC);
  for (int i = tid; i < 2048; i += 256) {
    int c2 = i & 31, t = i >> 5;
    base[(tb + 1 + t) * 32 + c2] = pack_bf16(ts[2 * c2][t], ts[2 * c2 + 1][t]);
  }
  // zero halo rows
  if (tb == 0 && tid < 32) base[tid] = 0u;
  if (tb == TLEN - 64 && tid < 32) base[513 * 32 + tid] = 0u;
}

__device__ __forceinline__ const char* slab_base(const __hip_bfloat16* xT,
                                                 int n, int vk, int tb) {
  return (const char*)xT + ((size_t)(n * NV + vk) * XT_ROWS + tb) * 128;
}

// Main: block = 64 o x 128 t for (tchunk, n, v). 4 waves: wave = (oslab, t-half).
// R7 lesson (Little's-law fit): per-wave latency ~18k cyc came from A-frag
// loads inside the compute loop (9 vmcnt windows x ~1.5k cyc remote-L2/L3).
// Fix: each wave owns ONE o-slab -> all 36 A-frags (144 VGPR) prefetched in a
// single burst BEFORE the one barrier; after it the 72-MFMA body is pure
// LDS+MFMA with no vmem dependency at all.
__global__ __launch_bounds__(256, 2) void lcn_mfma32(
    const __hip_bfloat16* __restrict__ xT,
    const __hip_bfloat16* __restrict__ Wt3,
    const float* __restrict__ bias,
    const int* __restrict__ idx,
    float* __restrict__ out) {
  __shared__ char xs[KK][XS_BYTES];   // 3 slabs, 49,920 B

  const int tb   = blockIdx.x * 128;
  const int n    = blockIdx.y;
  const int v    = blockIdx.z;
  const int tid  = threadIdx.x;
  const int lane = tid & 63;
  const int wave = tid >> 6;
  const int os   = wave & 1;     // this wave's o-slab
  const int th   = wave >> 1;    // this wave's 64-t half
  const int hi   = lane >> 5;
  const int l31  = lane & 31;

  // 1) issue async staging of all 3 neighbor slabs (no VGPR round-trip)
  {
    const char* g0 = slab_base(xT, n, idx[v * KK + 0], tb);
    const char* g1 = slab_base(xT, n, idx[v * KK + 1], tb);
    const char* g2 = slab_base(xT, n, idx[v * KK + 2], tb);
    for (int j = wave; j < 3 * 17; j += 4) {
      int slab = j / 17, c = j % 17;
      const char* gb = slab == 0 ? g0 : (slab == 1 ? g1 : g2);
      int L = c * 1024 + lane * 16;
      if (L < XS_BYTES) {
        int g = L ^ (((L >> 7) & 7) << 4);   // XOR bits 4-6 by row bits 7-9
        __builtin_amdgcn_global_load_lds(
            (const __attribute__((address_space(1))) void*)(gb + g),
            (__attribute__((address_space(3))) void*)(&xs[slab][c * 1024]),
            16, 0, 0);
      }
    }
  }

  // 2) prefetch ALL 36 A-frags for this wave's o-slab in one burst (144 VGPR);
  //    latency overlaps the staging drain at the barrier below.
  short8 a[9][4];
  {
    const short8* wb = (const short8*)Wt3 + ((size_t)(v * 9) * 2 + os) * 256 + lane;
#pragma unroll
    for (int bq = 0; bq < 9; ++bq)
#pragma unroll
      for (int ks = 0; ks < 4; ++ks)
        a[bq][ks] = wb[bq * 512 + (ks << 6)];
  }

  __syncthreads();   // the only barrier; drains staging + A-prefetch together

  f32x16 acc0 = {}, acc1 = {};   // t-subtile 0 / 1 of this wave's 64-t half

#pragma unroll
  for (int k = 0; k < KK; ++k) {
    const char* cb = xs[k];
#pragma unroll
    for (int kt = 0; kt < TKK; ++kt) {
      const int bq = k * TKK + kt;
      {
        const int r  = th * 64 + l31 + kt;
        const int sw = (r & 7) << 4;
        const int co = hi * 16;
        const char* bp = cb + r * 128;
#pragma unroll
        for (int ks = 0; ks < 4; ++ks) {
          short8 bfr = *(const short8*)(bp + ((co + 32 * ks) ^ sw));
          acc0 = __builtin_amdgcn_mfma_f32_32x32x16_bf16(a[bq][ks], bfr, acc0, 0, 0, 0);
        }
      }
      {
        const int r  = th * 64 + 32 + l31 + kt;
        const int sw = (r & 7) << 4;
        const int co = hi * 16;
        const char* bp = cb + r * 128;
#pragma unroll
        for (int ks = 0; ks < 4; ++ks) {
          short8 bfr = *(const short8*)(bp + ((co + 32 * ks) ^ sw));
          acc1 = __builtin_amdgcn_mfma_f32_32x32x16_bf16(a[bq][ks], bfr, acc1, 0, 0, 0);
        }
      }
    }
  }

  // epilogue: D col(t)=lane&31, row(o)=(reg&3)+8*(reg>>2)+4*(lane>>5)
  const float* bv = bias + v * COUTC;
#pragma unroll
  for (int s = 0; s < 2; ++s) {
    const f32x16& acc = s ? acc1 : acc0;
    const int t = tb + th * 64 + s * 32 + l31;
#pragma unroll
    for (int reg = 0; reg < 16; ++reg) {
      int o = os * 32 + 4 * hi + (reg & 3) + 8 * (reg >> 2);
      out[(((size_t)n * COUTC + o) * NV + v) * TLEN + t] = acc[reg] + bv[o];
    }
  }
}

// ================= FALLBACK PATH (round-1 fp32, known-good) =================
__global__ void prep_mask_kernel(const int* __restrict__ mask_raw,
                                 int* __restrict__ mask_out) {
  __shared__ int fmt;
  if (threadIdx.x == 0) {
    int ok = 1;
    for (int i = 0; i < 18; ++i) {
      int m = mask_raw[i];
      if (m != 0 && m != 1) ok = 0;
    }
    fmt = ok;
  }
  __syncthreads();
  int i = threadIdx.x;
  if (i < NV * KK) {
    int m;
    if (fmt) m = mask_raw[i];
    else     m = (((const unsigned char*)mask_raw)[i] != 0) ? 1 : 0;
    mask_out[i] = m;
  }
}

__global__ void prep_wt_kernel(const float* __restrict__ W,
                               float* __restrict__ Wt) {
  int v   = blockIdx.x / 9;
  int kkt = blockIdx.x % 9;
  const float* Wv = W + (size_t)v * COUTC * CINC * 9;
  float* dst = Wt + (size_t)blockIdx.x * (CINC * COUTC);
  for (int i = threadIdx.x; i < CINC * COUTC; i += 256) {
    int c = i >> 6;
    int o = i & 63;
    dst[i] = Wv[(o * CINC + c) * 9 + kkt];
  }
}

__global__ __launch_bounds__(256, 4) void lcn_main(
    const float* __restrict__ x, const float* __restrict__ Wt,
    const float* __restrict__ b, const int* __restrict__ idx,
    const int* __restrict__ maskn, float* __restrict__ out) {
  __shared__ float xsf[CINC][66];
  __shared__ float wsh[CINC][COUTC];
  const int tb  = blockIdx.x * 64;
  const int v   = blockIdx.y;
  const int n   = blockIdx.z;
  const int tid = threadIdx.x;
  const int t0  = tid & 63;
  const int og  = tid >> 6;
  float acc[16];
#pragma unroll
  for (int j = 0; j < 16; ++j) acc[j] = 0.f;
  for (int k = 0; k < KK; ++k) {
    const int vk = idx[v * KK + k];
    const int mk = maskn[v * KK + k];
    __syncthreads();
    for (int i = tid; i < CINC * 66; i += 256) {
      int c  = i / 66;
      int tt = i - c * 66;
      int gt = tb - 1 + tt;
      float val = 0.f;
      if (mk && gt >= 0 && gt < TLEN)
        val = x[(((size_t)n * CINC + c) * NV + vk) * TLEN + gt];
      xsf[c][tt] = val;
    }
    for (int kt = 0; kt < TKK; ++kt) {
      __syncthreads();
      const float4* src =
          (const float4*)(Wt + ((size_t)(v * KK + k) * TKK + kt) * (CINC * COUTC));
      for (int i = tid; i < CINC * COUTC / 4; i += 256)
        ((float4*)wsh)[i] = src[i];
      __syncthreads();
#pragma unroll 4
      for (int c = 0; c < CINC; ++c) {
        float xv = xsf[c][t0 + kt];
        const float4* wrow = (const float4*)&wsh[c][og * 16];
#pragma unroll
        for (int j4 = 0; j4 < 4; ++j4) {
          float4 wv = wrow[j4];
          acc[j4 * 4 + 0] = fmaf(wv.x, xv, acc[j4 * 4 + 0]);
          acc[j4 * 4 + 1] = fmaf(wv.y, xv, acc[j4 * 4 + 1]);
          acc[j4 * 4 + 2] = fmaf(wv.z, xv, acc[j4 * 4 + 2]);
          acc[j4 * 4 + 3] = fmaf(wv.w, xv, acc[j4 * 4 + 3]);
        }
      }
    }
  }
#pragma unroll
  for (int j = 0; j < 16; ++j) {
    int o = og * 16 + j;
    out[(((size_t)n * COUTC + o) * NV + v) * TLEN + tb + t0] =
        acc[j] + b[v * COUTC + o];
  }
}

extern "C" void kernel_launch(void* const* d_in, const int* in_sizes, int n_in,
                              void* d_out, int out_size, void* d_ws, size_t ws_size,
                              hipStream_t stream) {
  const float* x    = (const float*)d_in[0];
  const float* W    = (const float*)d_in[1];
  const float* b    = (const float*)d_in[2];
  const int*   idx  = (const int*)d_in[3];
  const void*  mask = (const void*)d_in[4];
  float* out = (float*)d_out;

  // ws: [0,512) maskn (fallback) | Wt3 1.84MB | xT padded 26.3MB | guard
  const size_t WT3_BYTES = (size_t)NV * 9 * 4096 * sizeof(__hip_bfloat16);
  const size_t XT_BYTES  = (size_t)NB * NV * XT_ROWS * CINC * sizeof(__hip_bfloat16);
  const size_t NEED      = 512 + WT3_BYTES + XT_BYTES + 2048;

  if (ws_size >= NEED) {
    __hip_bfloat16* Wt3 = (__hip_bfloat16*)((char*)d_ws + 512);
    __hip_bfloat16* xT  = (__hip_bfloat16*)((char*)d_ws + 512 + WT3_BYTES);
    hipLaunchKernelGGL(prep_all, dim3(NWT3BLK + 8 * NV * NB), dim3(256), 0,
                       stream, x, W, (const unsigned char*)mask, Wt3, xT);
    hipLaunchKernelGGL(lcn_mfma32, dim3(TLEN / 128, NB, NV), dim3(256), 0,
                       stream, xT, Wt3, b, idx, out);
  } else {
    int*   maskn = (int*)d_ws;
    float* Wt    = (float*)((char*)d_ws + 512);
    hipLaunchKernelGGL(prep_mask_kernel, dim3(1), dim3(128), 0, stream,
                       (const int*)mask, maskn);
    hipLaunchKernelGGL(prep_wt_kernel, dim3(NV * KK * TKK), dim3(256), 0, stream,
                       W, Wt);
    hipLaunchKernelGGL(lcn_main, dim3(TLEN / 64, NV, NB), dim3(256), 0, stream,
                       x, Wt, b, idx, maskn, out);
  }
}